// Round 10
// baseline (136.926 us; speedup 1.0000x reference)
//
#include <hip/hip_runtime.h>

// SSIM (7x7 uniform window) over B=64, C=1, H=W=384 fp32 images.
// out = mean over interior 378x378 crop of all 64 images (scalar).
//
// R22 = 4-COLS-PER-LANE + recompute-evict. Empirical law from R14-R21:
// ssim time ~= 0.41us per 1000 wave-rows, INVARIANT across LDS/direct
// staging, occupancy 14-32%, VALU +-50% (R20) -> each wave-row costs
// ~1000cyc of exposed memory latency no matter its content. So shrink
// wave-rows: 4 cols/lane -> one band needs 2 waves (95 active lanes),
// not 3 -> wave-rows 92160 -> 61440 (-33%).
//   - ring infeasible at 4 cols (7x5xfloat4 = 140 VGPR) -> recompute-evict
//     (R20: its +50% VALU was NEUTRAL per-row; its loss was MORE wave-rows,
//     which this design reverses).
//   - lane L: cols 4L..4L+3, taps floats [oc..oc+9], oc = min(4L, 374)
//     (8B-aligned 5xfloat2 loads; in-row <= col 383). keep-mask
//     oc+k >= 4L dedups the clamped lanes; L>=95 fully masked.
//   - branchless emit (R21), 1 divide per 4 cols (pairwise fusion),
//     float acc, double only at partial store.
//   - grid (1,16,64) = 1024 blocks x 128 thr = 2048 waves x 30 rows.
//
// K1 max_kernel: max(gt) -> ws_max (monotone-encoded uint, atomicMax)
// K2 ssim_kernel: 1024 x 2-wave blocks, 4 cols/lane, direct taps, no LDS
// K3 final_kernel: sum partials, divide, store d_out[0]
//
// BANNED (measured): named-bank ping-pong macros (R19, 70MB scratch spill);
// LDS tap staging in ANY schedule (R12/R14/R15, ~43us); coop grid.sync
// fusion (R13, +192us); 12B global_load_lds (R10, absmax 0.21);
// launch_bounds cap BELOW live set (R4, 33MB spill); per-block
// __threadfence finalize (R3/R5); divergent per-row emit branch (fixed R21).

#define PADW 3
#define BT 128            // 2 waves per block; both waves share one band
#define BAND 24           // output rows per band
#define SROWS (BAND + 6)  // 30 swept rows

constexpr int B_ = 64, H_ = 384, W_ = 384;
constexpr int OUTD = W_ - 2 * PADW;                       // 378
constexpr int NBANDS = 16;                                // 16 x 24 = 384 >= 378
constexpr int TOTAL_PART = NBANDS * B_ * 2;               // 2048 wave partials
constexpr double NPIX = (double)B_ * OUTD * OUTD;         // 9,144,576

__device__ __forceinline__ unsigned enc_f(float f) {
    unsigned u = __float_as_uint(f);
    return (u & 0x80000000u) ? ~u : (u | 0x80000000u);
}
__device__ __forceinline__ float dec_f(unsigned e) {
    return __uint_as_float((e & 0x80000000u) ? (e & 0x7fffffffu) : ~e);
}

__global__ void __launch_bounds__(256)
max_kernel(const float4* __restrict__ g4, unsigned* ws_max, int n4) {
    int tid = blockIdx.x * blockDim.x + threadIdx.x;
    int stride = gridDim.x * blockDim.x;
    float m = -3.402823466e38f;
    for (int i = tid; i < n4; i += stride) {
        float4 v = g4[i];
        m = fmaxf(m, fmaxf(fmaxf(v.x, v.y), fmaxf(v.z, v.w)));
    }
#pragma unroll
    for (int off = 32; off > 0; off >>= 1)
        m = fmaxf(m, __shfl_down(m, off));
    __shared__ float sm[4];
    if ((threadIdx.x & 63) == 0) sm[threadIdx.x >> 6] = m;
    __syncthreads();
    if (threadIdx.x == 0) {
        float mm = fmaxf(fmaxf(sm[0], sm[1]), fmaxf(sm[2], sm[3]));
        // no zero-init needed: 0xAA poison = enc(+3e-13), dominated by enc(max)
        atomicMax(ws_max, enc_f(mm));
    }
}

// 49^4-rescaled SSIM numerator/denominator products (scale cancels in the
// ratio; exactly the reference formula).
__device__ __forceinline__ void ssim_nd(float a, float b, float sxx, float syy, float sxy,
                                        float C1q, float C2q, float& num, float& den) {
    const float covn = 49.0f / 48.0f;
    float ab   = a * b;
    float num1 = fmaf(2.0f, ab, C1q);
    float txy  = fmaf(49.0f, sxy, -ab);
    float num2 = fmaf(2.0f * covn, txy, C2q);
    float b2   = b * b;
    float aabb = fmaf(a, a, b2);
    float den1 = aabb + C1q;
    float spq  = sxx + syy;
    float tv   = fmaf(49.0f, spq, -aabb);
    float den2 = fmaf(covn, tv, C2q);
    num = num1 * num2;
    den = den1 * den2;
}

__global__ void __launch_bounds__(BT)
ssim_kernel(const float* __restrict__ gt, const float* __restrict__ pred,
            const unsigned* __restrict__ ws_max, double* __restrict__ ws_part) {
    const int t    = threadIdx.x;          // 0..127
    const int lane = t & 63;
    const int wid  = t >> 6;               // 0/1
    const int band = blockIdx.y;           // 0..15
    const int b    = blockIdx.z;           // 0..63
    const int bid  = (b * NBANDS + band) * 2 + wid;

    const float dr  = dec_f(*ws_max);
    const float c1  = 0.01f * dr, c2 = 0.03f * dr;
    const float C1q = c1 * c1 * 2401.0f;   // C1 * 49^2
    const float C2q = c2 * c2 * 2401.0f;   // C2 * 49^2

    const int row0 = band * BAND;

    // lane's 4 output cols: oc..oc+3, taps = floats [oc..oc+9] (in-row: <=383).
    // clamp keeps lanes 94..127 in bounds; keep-mask dedups/disables them.
    const int oc = min(4 * t, W_ - 10);    // 374 for t>=94; even -> 8B-aligned
    bool keepc[4];
#pragma unroll
    for (int k = 0; k < 4; ++k)
        keepc[k] = (oc + k >= 4 * t) && (oc + k < OUTD);

    const float* gimg = gt   + (size_t)b * H_ * W_;
    const float* pimg = pred + (size_t)b * H_ * W_;

    // vertical window sums for 4 cols x 5 moments (all indices static)
    float vx[4], vy[4], vxx[4], vyy[4], vxy[4];
#pragma unroll
    for (int k = 0; k < 4; ++k) { vx[k]=0.f; vy[k]=0.f; vxx[k]=0.f; vyy[k]=0.f; vxy[k]=0.f; }
    float acc = 0.0f;

    // load row ir's 10 taps per array, produce 5 horizontal 7-tap sums for
    // the 4 cols (col0 tree + 3 slides). IDENTICAL instruction DAG every
    // call -> recomputed evict values bitwise-equal to what was inserted.
    auto calc = [&](int ir, float hx[4], float hy[4],
                    float hxx[4], float hyy[4], float hxy[4]) {
        const float* gp_ = gimg + ir * W_ + oc;
        const float* pp_ = pimg + ir * W_ + oc;
        float tp[10], up[10];
#pragma unroll
        for (int m = 0; m < 5; ++m) {
            float2 a  = *(const float2*)(gp_ + 2 * m);
            float2 b2 = *(const float2*)(pp_ + 2 * m);
            tp[2*m] = a.x;  tp[2*m+1] = a.y;
            up[2*m] = b2.x; up[2*m+1] = b2.y;
        }
        float sx = tp[0], sy = up[0];
        float sxx = tp[0]*tp[0], syy = up[0]*up[0], sxy = tp[0]*up[0];
#pragma unroll
        for (int m = 1; m < 7; ++m) {
            sx += tp[m]; sy += up[m];
            sxx = fmaf(tp[m], tp[m], sxx);
            syy = fmaf(up[m], up[m], syy);
            sxy = fmaf(tp[m], up[m], sxy);
        }
        hx[0]=sx; hy[0]=sy; hxx[0]=sxx; hyy[0]=syy; hxy[0]=sxy;
#pragma unroll
        for (int k = 1; k < 4; ++k) {      // slide: -tap(k-1) +tap(k+6)
            sx  = sx - tp[k-1] + tp[k+6];
            sy  = sy - up[k-1] + up[k+6];
            sxx = fmaf(tp[k+6], tp[k+6], fmaf(-tp[k-1], tp[k-1], sxx));
            syy = fmaf(up[k+6], up[k+6], fmaf(-up[k-1], up[k-1], syy));
            sxy = fmaf(tp[k+6], up[k+6], fmaf(-up[k-1], tp[k-1], sxy));
            hx[k]=sx; hy[k]=sy; hxx[k]=sxx; hyy[k]=syy; hxy[k]=sxy;
        }
    };

    // branchless emit for output row orow (R21): masked lanes/rows add 0
    auto emit = [&](int orow) {
        const bool rowok = orow < OUTD;
        float n[4], d[4];
#pragma unroll
        for (int k = 0; k < 4; ++k) {
            ssim_nd(vx[k], vy[k], vxx[k], vyy[k], vxy[k], C1q, C2q, n[k], d[k]);
            n[k] = (rowok && keepc[k]) ? n[k] : 0.0f;   // d[k] > 0 always
        }
        // sum of 4 fractions with ONE divide
        float N01 = fmaf(n[0], d[1], n[1] * d[0]), D01 = d[0] * d[1];
        float N23 = fmaf(n[2], d[3], n[3] * d[2]), D23 = d[2] * d[3];
        acc += fmaf(N01, D23, N23 * D01) / (D01 * D23);
    };

    float hx[4], hy[4], hxx[4], hyy[4], hxy[4];
    float ex[4], ey[4], exx[4], eyy[4], exy[4];

    // ---- fill: insert rows 0..6 (v += h, bitwise = window sum) ----
#pragma unroll 1
    for (int i = 0; i < 7; ++i) {
        calc(min(row0 + i, H_ - 1), hx, hy, hxx, hyy, hxy);
#pragma unroll
        for (int k = 0; k < 4; ++k) {
            vx[k] += hx[k]; vy[k] += hy[k]; vxx[k] += hxx[k];
            vyy[k] += hyy[k]; vxy[k] += hxy[k];
        }
    }
    emit(row0);

    // ---- steady state: insert row i, evict row i-7 (recomputed, L2-hot:
    // this wave loaded those taps 7 iterations ago), emit row0+i-6 ----
#pragma unroll 1
    for (int i = 7; i < SROWS; ++i) {
        calc(min(row0 + i, H_ - 1),     hx, hy, hxx, hyy, hxy);
        calc(min(row0 + i - 7, H_ - 1), ex, ey, exx, eyy, exy);
#pragma unroll
        for (int k = 0; k < 4; ++k) {
            vx[k]  += hx[k]  - ex[k];
            vy[k]  += hy[k]  - ey[k];
            vxx[k] += hxx[k] - exx[k];
            vyy[k] += hyy[k] - eyy[k];
            vxy[k] += hxy[k] - exy[k];
        }
        emit(row0 + i - 6);
    }

    // per-wave reduction (float) -> one double store per wave (no atomics)
#pragma unroll
    for (int off2 = 32; off2 > 0; off2 >>= 1)
        acc += __shfl_down(acc, off2);
    if (lane == 0) ws_part[bid] = (double)acc;
}

__global__ void __launch_bounds__(256)
final_kernel(const double* __restrict__ ws_part, float* __restrict__ out) {
    const int t = threadIdx.x;
    double s = 0.0;
    for (int i = t; i < TOTAL_PART; i += 256) s += ws_part[i];
#pragma unroll
    for (int off = 32; off > 0; off >>= 1)
        s += __shfl_down(s, off);
    __shared__ double sd[4];
    if ((t & 63) == 0) sd[t >> 6] = s;
    __syncthreads();
    if (t == 0) out[0] = (float)((sd[0] + sd[1] + sd[2] + sd[3]) / NPIX);
}

extern "C" void kernel_launch(void* const* d_in, const int* in_sizes, int n_in,
                              void* d_out, int out_size, void* d_ws, size_t ws_size,
                              hipStream_t stream) {
    const float* gt   = (const float*)d_in[0];
    const float* pred = (const float*)d_in[1];
    // d_in[2] is the uniform 1/49 window -> constant-folded into the kernel.
    float* out = (float*)d_out;

    unsigned* ws_max  = (unsigned*)d_ws;                   // offset 0 (4 B)
    double*   ws_part = (double*)((char*)d_ws + 64);       // 2048 doubles (16 KB)

    // no memset: 0xAA poison is benign for atomicMax (enc-space +3e-13),
    // and ws_part is fully written by ssim_kernel before final_kernel reads.

    const int n4 = B_ * H_ * W_ / 4;  // 2,359,296 float4s
    max_kernel<<<1024, 256, 0, stream>>>((const float4*)gt, ws_max, n4);

    dim3 grid(1, NBANDS, B_);         // 1 x 16 x 64 = 1024 two-wave blocks
    ssim_kernel<<<grid, BT, 0, stream>>>(gt, pred, ws_max, ws_part);

    final_kernel<<<1, 256, 0, stream>>>(ws_part, out);
}

// Round 11
// 131.699 us; speedup vs baseline: 1.0397x; 1.0397x over previous
//
#include <hip/hip_runtime.h>

// SSIM (7x7 uniform window) over B=64, C=1, H=W=384 fp32 images.
// out = mean over interior 378x378 crop of all 64 images (scalar).
//
// R23 = R21 (best 129.3us: no-LDS direct-tap, 4-wave blocks, BAND 24,
// lb(256,3), fused div, float acc, branchless emit) + PAIR-BATCHED LOADS.
// Consolidated model (R14-R22): each row body issues 8 loads and waits on
// them immediately -> ~1 exposed memory round-trip PER ROW per wave;
// occupancy (2-5 waves/SIMD), VALU content (+-50%), staging scheme all
// secondary. R21 proved the compiler does NOT hoist loads across row
// bodies on its own (straight-line change: only -2us); R19 forced per-row
// pipelining across a runtime loop boundary and spilled (70MB scratch).
// R23 forces it SPILL-SAFELY: within each unrolled 7-row group, load BOTH
// rows of a pair into named Taps structs BEFORE computing either:
//     A=ldrow(i); B=ldrow(i+1); dorow(A,i); dorow(B,i+1);
// B's latency hides under A's ~230cyc compute -> exposed stall per 2 rows
// instead of per row. Live: 2 Taps = 32 VGPR + ring 70 + misc ~30 = ~132
// < 170 cap; no values live across runtime loop boundaries (unlike R19).
// Groups of 7 = pairs (0,1)(2,3)(4,5) + row 6; ring slots compile-time;
// tail rows 28,29 form a natural pair (slots 0,1).
//
// K1 max_kernel: max(gt) -> ws_max (monotone-encoded uint, atomicMax)
// K2 ssim_kernel: 768 x 4-wave blocks, direct global taps, no LDS
// K3 final_kernel: sum partials, divide, store d_out[0]
//
// BANNED (measured): 4-col/lane at <3 waves/SIMD supplied (R22, 44.5us);
// ring-free recompute-evict at same wave count (R20, +50% VALU = +6us);
// cross-runtime-loop ping-pong banks (R19, 70MB scratch spill); LDS tap
// staging in ANY schedule (R12/R14/R15, ~43us); coop grid.sync fusion
// (R13, +192us); 12B global_load_lds (R10); launch_bounds cap BELOW live
// set (R4); per-block __threadfence finalize (R3/R5); divergent per-row
// emit branch (fixed R21).

#define PADW 3
#define BT 256            // threads per block = 4 waves; wave w owns one band
#define WPB 4             // waves per block
#define BAND 24           // output rows per wave
#define SROWS (BAND + 6)  // 30 swept rows = 4 x 7 + 2

constexpr int B_ = 64, H_ = 384, W_ = 384;
constexpr int W2 = W_ / 2;                                // row length in float2
constexpr int OUTD = W_ - 2 * PADW;                       // 378
constexpr int NBANDS = 16;                                // 16 x 24 = 384 >= 378
constexpr int NBGRP  = NBANDS / WPB;                      // 4 band-groups
constexpr int NTILES = 3;                                 // 3 x 126 cols = 378
constexpr int TOTAL_PART = NTILES * NBANDS * B_;          // 3072 partials
constexpr double NPIX = (double)B_ * OUTD * OUTD;         // 9,144,576

__device__ __forceinline__ unsigned enc_f(float f) {
    unsigned u = __float_as_uint(f);
    return (u & 0x80000000u) ? ~u : (u | 0x80000000u);
}
__device__ __forceinline__ float dec_f(unsigned e) {
    return __uint_as_float((e & 0x80000000u) ? (e & 0x7fffffffu) : ~e);
}

__device__ __forceinline__ float2 f2add(float2 a, float2 b) { return make_float2(a.x + b.x, a.y + b.y); }
__device__ __forceinline__ float2 f2sub(float2 a, float2 b) { return make_float2(a.x - b.x, a.y - b.y); }

__global__ void __launch_bounds__(256)
max_kernel(const float4* __restrict__ g4, unsigned* ws_max, int n4) {
    int tid = blockIdx.x * blockDim.x + threadIdx.x;
    int stride = gridDim.x * blockDim.x;
    float m = -3.402823466e38f;
    for (int i = tid; i < n4; i += stride) {
        float4 v = g4[i];
        m = fmaxf(m, fmaxf(fmaxf(v.x, v.y), fmaxf(v.z, v.w)));
    }
#pragma unroll
    for (int off = 32; off > 0; off >>= 1)
        m = fmaxf(m, __shfl_down(m, off));
    __shared__ float sm[4];
    if ((threadIdx.x & 63) == 0) sm[threadIdx.x >> 6] = m;
    __syncthreads();
    if (threadIdx.x == 0) {
        float mm = fmaxf(fmaxf(sm[0], sm[1]), fmaxf(sm[2], sm[3]));
        // no zero-init needed: 0xAA poison = enc(+3e-13), dominated by enc(max)
        atomicMax(ws_max, enc_f(mm));
    }
}

// 49^4-rescaled SSIM numerator/denominator products (scale cancels in the
// ratio; exactly the reference formula).
__device__ __forceinline__ void ssim_nd(float a, float b, float sxx, float syy, float sxy,
                                        float C1q, float C2q, float& num, float& den) {
    const float covn = 49.0f / 48.0f;
    float ab   = a * b;
    float num1 = fmaf(2.0f, ab, C1q);
    float txy  = fmaf(49.0f, sxy, -ab);
    float num2 = fmaf(2.0f * covn, txy, C2q);
    float b2   = b * b;
    float aabb = fmaf(a, a, b2);
    float den1 = aabb + C1q;
    float spq  = sxx + syy;
    float tv   = fmaf(49.0f, spq, -aabb);
    float den2 = fmaf(covn, tv, C2q);
    num = num1 * num2;
    den = den1 * den2;
}

struct Taps { float2 d0, d1, d2, d3, e0, e1, e2, e3; };

__global__ void __launch_bounds__(BT, 3)
ssim_kernel(const float* __restrict__ gt, const float* __restrict__ pred,
            const unsigned* __restrict__ ws_max, double* __restrict__ ws_part) {
    const int t    = threadIdx.x;
    const int lane = t & 63;
    const int wave = t >> 6;               // 0..3
    const int tile = blockIdx.x;           // 0..2 column tiles (126 out cols)
    const int band = blockIdx.y * WPB + wave;   // 0..15, one band per wave
    const int b    = blockIdx.z;           // 0..63 images
    const int bid  = (b * NBANDS + band) * NTILES + tile;

    const float dr  = dec_f(*ws_max);
    const float c1  = 0.01f * dr, c2 = 0.03f * dr;
    const float C1q = c1 * c1 * 2401.0f;   // C1 * 49^2
    const float C2q = c2 * c2 * 2401.0f;   // C2 * 49^2

    const int  row0   = band * BAND;
    const bool active = (lane < 63);  // lane -> out cols tile*126+2*lane, +1

    // thread's tap base (float2 index in row): floats 2*tb .. 2*tb+7 cover
    // both columns' 7-tap windows. Clamp keeps lane 63 in-row on tile 2.
    const int tb = min(tile * 63 + lane, W2 - 4);

    const float2* gp = (const float2*)(gt   + (size_t)b * H_ * W_) + tb;
    const float2* pp = (const float2*)(pred + (size_t)b * H_ * W_) + tb;

    // vertical ring of horizontal 7-tap sums (2 columns packed in float2).
    float2 rx[7], ry[7], rxx[7], ryy[7], rxy[7];
#pragma unroll
    for (int j = 0; j < 7; ++j) {
        rx[j] = make_float2(0.f, 0.f); ry[j] = rx[j];
        rxx[j] = rx[j]; ryy[j] = rx[j]; rxy[j] = rx[j];
    }
    float2 vx = make_float2(0.f, 0.f), vy = vx, vxx = vx, vyy = vx, vxy = vx;
    float acc = 0.0f;   // per-thread sum <= 48; double only at partial store

    // issue one row's 8 tap loads (pure address dependence -> schedulable
    // as a batch; result lands in a named struct, SROA'd to 16 VGPRs)
    auto ldrow = [&](int i) {
        const int ir = min(row0 + i, H_ - 1);        // clamped image row
        const float2* gr = gp + (size_t)ir * W2;
        const float2* pr = pp + (size_t)ir * W2;
        Taps T;
        T.d0 = gr[0]; T.d1 = gr[1]; T.d2 = gr[2]; T.d3 = gr[3];
        T.e0 = pr[0]; T.e1 = pr[1]; T.e2 = pr[2]; T.e3 = pr[3];
        return T;
    };

    // consume a loaded row: slide windows, emit output row i-6 (branchless)
    auto dorow = [&](const Taps& T, int i, int slot) {
        float2 d0 = T.d0, d1 = T.d1, d2 = T.d2, d3 = T.d3;
        float2 e0 = T.e0, e1 = T.e1, e2 = T.e2, e3 = T.e3;

        float hx0 = d0.x + d0.y + d1.x + d1.y + d2.x + d2.y + d3.x;
        float hy0 = e0.x + e0.y + e1.x + e1.y + e2.x + e2.y + e3.x;
        float hxx0 = fmaf(d0.x, d0.x, fmaf(d0.y, d0.y, fmaf(d1.x, d1.x,
                     fmaf(d1.y, d1.y, fmaf(d2.x, d2.x, fmaf(d2.y, d2.y, d3.x * d3.x))))));
        float hyy0 = fmaf(e0.x, e0.x, fmaf(e0.y, e0.y, fmaf(e1.x, e1.x,
                     fmaf(e1.y, e1.y, fmaf(e2.x, e2.x, fmaf(e2.y, e2.y, e3.x * e3.x))))));
        float hxy0 = fmaf(d0.x, e0.x, fmaf(d0.y, e0.y, fmaf(d1.x, e1.x,
                     fmaf(d1.y, e1.y, fmaf(d2.x, e2.x, fmaf(d2.y, e2.y, d3.x * e3.x))))));

        // horizontal slide for the second column: -tap0 +tap7
        float2 h_x  = make_float2(hx0,  hx0  - d0.x        + d3.y);
        float2 h_y  = make_float2(hy0,  hy0  - e0.x        + e3.y);
        float2 h_xx = make_float2(hxx0, hxx0 - d0.x * d0.x + d3.y * d3.y);
        float2 h_yy = make_float2(hyy0, hyy0 - e0.x * e0.x + e3.y * e3.y);
        float2 h_xy = make_float2(hxy0, hxy0 - d0.x * e0.x + d3.y * e3.y);

        // vertical sliding window: evict slot (holds row i-7), insert row i
        vx  = f2add(vx,  f2sub(h_x,  rx[slot]));  rx[slot]  = h_x;
        vy  = f2add(vy,  f2sub(h_y,  ry[slot]));  ry[slot]  = h_y;
        vxx = f2add(vxx, f2sub(h_xx, rxx[slot])); rxx[slot] = h_xx;
        vyy = f2add(vyy, f2sub(h_yy, ryy[slot])); ryy[slot] = h_yy;
        vxy = f2add(vxy, f2sub(h_xy, rxy[slot])); rxy[slot] = h_xy;

        if (i >= 6) {   // compile-time: rows 0..5 emit nothing at all
            const int orow = row0 + i - 6;
            float na, da, nb, db;
            ssim_nd(vx.x, vy.x, vxx.x, vyy.x, vxy.x, C1q, C2q, na, da);
            ssim_nd(vx.y, vy.y, vxx.y, vyy.y, vxy.y, C1q, C2q, nb, db);
            float val = fmaf(na, db, nb * da) / (da * db);
            bool keep = active && (orow < OUTD);   // v_cndmask, no branch
            acc += keep ? val : 0.0f;
        }
    };

    // sweep 30 rows: 4 groups x 7 (pairs (0,1)(2,3)(4,5) + row 6; ring slot
    // = j compile-time) + 2-row tail pair (slots 28%7=0, 29%7=1).
    // Pair batching: both rows' 16 loads issue before either compute ->
    // one exposed round-trip per PAIR, B hidden under A's compute.
#pragma unroll 1
    for (int g = 0; g < 4; ++g) {
        const int gi = g * 7;
#pragma unroll
        for (int jp = 0; jp < 3; ++jp) {
            Taps A = ldrow(gi + 2 * jp);
            Taps B = ldrow(gi + 2 * jp + 1);
            dorow(A, gi + 2 * jp,     2 * jp);
            dorow(B, gi + 2 * jp + 1, 2 * jp + 1);
        }
        Taps C = ldrow(gi + 6);
        dorow(C, gi + 6, 6);
    }
    {
        Taps A = ldrow(28);
        Taps B = ldrow(29);
        dorow(A, 28, 0);
        dorow(B, 29, 1);
    }

    // per-wave reduction (float) -> one double store per wave (no atomics)
#pragma unroll
    for (int off2 = 32; off2 > 0; off2 >>= 1)
        acc += __shfl_down(acc, off2);
    if (lane == 0) ws_part[bid] = (double)acc;
}

__global__ void __launch_bounds__(256)
final_kernel(const double* __restrict__ ws_part, float* __restrict__ out) {
    const int t = threadIdx.x;
    double s = 0.0;
    for (int i = t; i < TOTAL_PART; i += 256) s += ws_part[i];
#pragma unroll
    for (int off = 32; off > 0; off >>= 1)
        s += __shfl_down(s, off);
    __shared__ double sd[4];
    if ((t & 63) == 0) sd[t >> 6] = s;
    __syncthreads();
    if (t == 0) out[0] = (float)((sd[0] + sd[1] + sd[2] + sd[3]) / NPIX);
}

extern "C" void kernel_launch(void* const* d_in, const int* in_sizes, int n_in,
                              void* d_out, int out_size, void* d_ws, size_t ws_size,
                              hipStream_t stream) {
    const float* gt   = (const float*)d_in[0];
    const float* pred = (const float*)d_in[1];
    // d_in[2] is the uniform 1/49 window -> constant-folded into the kernel.
    float* out = (float*)d_out;

    unsigned* ws_max  = (unsigned*)d_ws;                   // offset 0 (4 B)
    double*   ws_part = (double*)((char*)d_ws + 64);       // 3072 doubles (~24 KB)

    // no memset: 0xAA poison is benign for atomicMax (enc-space +3e-13),
    // and ws_part is fully written by ssim_kernel before final_kernel reads.

    const int n4 = B_ * H_ * W_ / 4;  // 2,359,296 float4s
    max_kernel<<<1024, 256, 0, stream>>>((const float4*)gt, ws_max, n4);

    dim3 grid(NTILES, NBGRP, B_);     // col tiles x band-groups x images
    ssim_kernel<<<grid, BT, 0, stream>>>(gt, pred, ws_max, ws_part);

    final_kernel<<<1, 256, 0, stream>>>(ws_part, out);
}